// Round 3
// baseline (1879.166 us; speedup 1.0000x reference)
//
#include <hip/hip_runtime.h>
#include <hip/hip_bf16.h>
#include <cstdint>
#include <cstddef>
#include <cmath>

#define TID ((int)threadIdx.x)
typedef __hip_bfloat16 bf16;

__device__ __forceinline__ float sigmf(float x){ return 1.0f/(1.0f + __expf(-x)); }
__device__ __forceinline__ float b2f(bf16 x){ return __bfloat162float(x); }
__device__ __forceinline__ bf16 f2b(float x){ return __float2bfloat16(x); }

// ---------------- K1a: P[rows,400] = emb[rows,100] @ Wih^T[100,400] + b  (f32 in, bf16 out)
__global__ __launch_bounds__(256) void k_proj(const float* __restrict__ emb,
        const float* __restrict__ Wih, const float* __restrict__ bias,
        bf16* __restrict__ P, int rows)
{
    __shared__ float el[16][100];
    int r0 = blockIdx.x * 16;
    for (int i = TID; i < 1600; i += 256){
        int r = i / 100, k = i - r*100;
        int rr = r0 + r;
        el[r][k] = (rr < rows) ? emb[rr*100 + k] : 0.0f;
    }
    __syncthreads();
    for (int g = TID; g < 400; g += 256){
        float b = bias[g];
        float acc[16];
#pragma unroll
        for (int r=0;r<16;r++) acc[r]=0.f;
        for (int k=0;k<100;k++){
            float w = Wih[g*100+k];
#pragma unroll
            for (int r=0;r<16;r++) acc[r] += el[r][k]*w;
        }
        for (int r=0;r<16;r++){
            int rr = r0+r;
            if (rr < rows) P[(size_t)rr*400+g] = f2b(acc[r] + b);
        }
    }
}

// ---------------- K1b: WT[k*400+g] = Whh[g*100+k]   (f32 -> f32)
__global__ __launch_bounds__(256) void k_transpose(const float* __restrict__ W, float* __restrict__ WT)
{
    int i = blockIdx.x*256 + TID;
    if (i < 40000){
        int k = i / 400;
        int g = i - k*400;
        WT[i] = W[g*100 + k];
    }
}

// ---------------- K1c: wa[f]=sum_o W[f,o]*a[o], wb[f]=sum_o W[f,o]*a[dim+o]  (f32)
__global__ __launch_bounds__(256) void k_wvec(const float* __restrict__ W, const float* __restrict__ a,
        float* __restrict__ wa, float* __restrict__ wb, int dim)
{
    int f = blockIdx.x*256 + TID;
    if (f >= dim) return;
    float x=0.f, y=0.f;
    for (int o=0;o<dim;o++){
        float w = W[(size_t)f*dim + o];
        x += w*a[o];
        y += w*a[dim+o];
    }
    wa[f]=x; wb[f]=y;
}

// ---------------- K2: fully fused per-group kernel ----------------
// One block = one attention group of 40 samples. All h states in LDS (bf16).
// HO[n][0..599]   : BiLSTM out row (t*200+[0..99]=fwd_t, t*200+100+[0..99]=bwd slot ob_t)
// HO[n][600..699] : process-LSTM working h
// Sample-0 rows of even groups additionally written f32-direct to out0/op0.
__global__ __launch_bounds__(256) void k_fused(
    const int* __restrict__ bh, const int* __restrict__ br, const int* __restrict__ bt,
    const bf16* __restrict__ Pfe, const bf16* __restrict__ Pfr,
    const bf16* __restrict__ Pbe, const bf16* __restrict__ Pbr,
    const bf16* __restrict__ Ppe, const bf16* __restrict__ Ppr,
    const float* __restrict__ WTf, const float* __restrict__ WTb, const float* __restrict__ WTp,
    const float* __restrict__ w1a, const float* __restrict__ w1b,
    const float* __restrict__ w2a, const float* __restrict__ w2b,
    float* __restrict__ z, float* __restrict__ z2,
    float* __restrict__ out0, float* __restrict__ op0)
{
    __shared__ bf16 HO[40][704];
    __shared__ float sc1[40], tc1[40], sc2[40], tc2[40];
    __shared__ float att1[40], att2[40];
    __shared__ int sidx[3][40];

    int g = blockIdx.x;
    int m0 = g*40;
    if (TID < 40){
        sidx[0][TID] = bh[m0+TID];
        sidx[1][TID] = br[m0+TID];
        sidx[2][TID] = bt[m0+TID];
    }
    __syncthreads();

    int jj = TID & 127;        // feature 0..99 (128-thread half)
    int sh = TID >> 7;         // which half: samples sh*20 .. sh*20+19
    int sbase = sh*20;
    bool act = jj < 100;
    bool doS0 = ((g & 1) == 0) && (sh == 0);   // even group, first half owns sample 0
    int r = g >> 1;

    const bf16* PeA[3] = {Pfe, Pbe, Ppe};
    const bf16* PrA[3] = {Pfr, Pbr, Ppr};
    const float* WTA[3] = {WTf, WTb, WTp};

    float c[20];

    for (int l=0; l<3; l++){
        const float* WT = WTA[l];
        for (int t=0; t<3; t++){
            float g0[20], g1[20], g2[20], g3[20];
#pragma unroll
            for (int s=0;s<20;s++){ g0[s]=0.f; g1[s]=0.f; g2[s]=0.f; g3[s]=0.f; }
            if (t > 0 && act){
                int koff = (l==0) ? (t-1)*200 : (l==1) ? (3-t)*200+100 : 600;
                for (int k=0;k<100;k++){
                    const float* wp = WT + k*400 + jj;
                    float w0=wp[0], w1=wp[100], w2=wp[200], w3=wp[300];
#pragma unroll
                    for (int s=0;s<20;s++){
                        float hv = b2f(HO[sbase+s][koff+k]);
                        g0[s] += hv*w0; g1[s] += hv*w1; g2[s] += hv*w2; g3[s] += hv*w3;
                    }
                }
            }
            __syncthreads();   // all LDS reads of prev h done before overwrite
            if (act){
                int p = (l==1) ? (2-t) : t;               // bwd consumes reversed seq
                const bf16* tab = (p==1) ? PrA[l] : PeA[l];
                int wslot = (l==0) ? t*200+jj : (l==1) ? (2-t)*200+100+jj : 600+jj;
#pragma unroll
                for (int s=0;s<20;s++){
                    int n = sbase+s;
                    const bf16* pp = tab + (size_t)sidx[p][n]*400 + jj;
                    float gi = g0[s]+b2f(pp[0]);
                    float gf = g1[s]+b2f(pp[100]);
                    float gg = g2[s]+b2f(pp[200]);
                    float go = g3[s]+b2f(pp[300]);
                    float cp = (t==0) ? 0.f : c[s];
                    float cn = sigmf(gf)*cp + sigmf(gi)*tanhf(gg);
                    float h  = sigmf(go)*tanhf(cn);
                    c[s] = cn;
                    HO[n][wslot] = f2b(h);
                    if (doS0 && s==0){
                        if (l < 2)       out0[(size_t)r*600 + wslot] = h;  // wslot includes jj
                        else if (t == 2) op0[(size_t)r*100 + jj] = h;
                    }
                }
            }
            __syncthreads();   // new h visible before next step's GEMM
        }
    }

    // ---- attention score dots: s1/t1 over 600-dim BiLSTM row, s2/t2 over 100-dim proc row
    int lane = TID & 63;
    int wv   = TID >> 6;
    for (int n = wv; n < 40; n += 4){
        float a=0.f, b=0.f;
        for (int k=lane;k<600;k+=64){ float v=b2f(HO[n][k]); a += v*w1a[k]; b += v*w1b[k]; }
#pragma unroll
        for (int off=32; off>0; off>>=1){ a += __shfl_down(a,off,64); b += __shfl_down(b,off,64); }
        if (lane==0){ sc1[n]=a; tc1[n]=b; }
        float a2=0.f, b2=0.f;
        for (int k=lane;k<100;k+=64){ float v=b2f(HO[n][600+k]); a2 += v*w2a[k]; b2 += v*w2b[k]; }
#pragma unroll
        for (int off=32; off>0; off>>=1){ a2 += __shfl_down(a2,off,64); b2 += __shfl_down(b2,off,64); }
        if (lane==0){ sc2[n]=a2; tc2[n]=b2; }
    }
    __syncthreads();

    // ---- softmax(leaky_relu(s_n + t_0)) over 40 samples, minus MU, relu
    if (wv < 2){
        const float* sc = (wv==0)? sc1 : sc2;
        const float* tc = (wv==0)? tc1 : tc2;
        float* av       = (wv==0)? att1 : att2;
        float e = -1e30f;
        if (lane < 40){
            float x = sc[lane] + tc[0];
            e = (x > 0.f) ? x : 0.2f*x;
        }
        float mx = e;
#pragma unroll
        for (int off=32;off>0;off>>=1) mx = fmaxf(mx, __shfl_down(mx,off,64));
        mx = __shfl(mx, 0, 64);
        float pexp = (lane<40) ? __expf(e-mx) : 0.f;
        float sm = pexp;
#pragma unroll
        for (int off=32;off>0;off>>=1) sm += __shfl_down(sm,off,64);
        sm = __shfl(sm, 0, 64);
        if (lane < 40){
            float a = pexp/sm - 0.001f;
            av[lane] = (a > 0.f) ? a : 0.f;
        }
    }
    __syncthreads();

    // ---- z = sum_n att1[n]*HO[n][:600]  and z2 = sum_n att2[n]*HO[n][600:700]
    for (int j=TID; j<600; j+=256){
        float acc = 0.f;
#pragma unroll
        for (int n=0;n<40;n++) acc += att1[n]*b2f(HO[n][j]);
        z[(size_t)g*600 + j] = acc;
    }
    for (int j=TID; j<100; j+=256){
        float acc = 0.f;
#pragma unroll
        for (int n=0;n<40;n++) acc += att2[n]*b2f(HO[n][600+j]);
        z2[(size_t)g*100 + j] = acc;
    }
}

// ---------------- K3: final GEMM  o[2048,dim] = z[2048,dim](f32) @ W[dim,dim](f32) -> f32
__global__ __launch_bounds__(256) void k_fgemm(const float* __restrict__ zz, const float* __restrict__ W,
    float* __restrict__ o, int dim)
{
    extern __shared__ float zl[]; // [16][dim]
    int rb = blockIdx.x*16;
    for (int r=0;r<16;r++){
        for (int j=TID;j<dim;j+=256) zl[r*dim+j] = zz[(size_t)(rb+r)*dim + j];
    }
    __syncthreads();
    int cc = blockIdx.y*256 + TID;
    if (cc < dim){
        float acc[16];
#pragma unroll
        for (int r=0;r<16;r++) acc[r]=0.f;
        for (int k=0;k<dim;k++){
            float w = W[(size_t)k*dim + cc];
#pragma unroll
            for (int r=0;r<16;r++) acc[r] += zl[r*dim+k]*w;
        }
        for (int r=0;r<16;r++) o[(size_t)(rb+r)*dim + cc] = acc[r];
    }
}

// ws-too-small sentinel: reports ws_size itself as the absmax for diagnosis
__global__ void k_sentinel(float* o, float v){ o[0] = v; }

extern "C" void kernel_launch(void* const* d_in, const int* in_sizes, int n_in,
                              void* d_out, int out_size, void* d_ws, size_t ws_size,
                              hipStream_t stream)
{
    const int*   bh   = (const int*)d_in[0];
    const int*   br   = (const int*)d_in[1];
    const int*   bt   = (const int*)d_in[2];
    const float* ent  = (const float*)d_in[3];
    const float* rel  = (const float*)d_in[4];
    const float* ent1 = (const float*)d_in[5];
    const float* rel1 = (const float*)d_in[6];
    const float* Wih_f = (const float*)d_in[7];
    const float* Whh_f = (const float*)d_in[8];
    const float* b_f   = (const float*)d_in[9];
    const float* Wih_b = (const float*)d_in[10];
    const float* Whh_b = (const float*)d_in[11];
    const float* b_b   = (const float*)d_in[12];
    const float* Wih_p = (const float*)d_in[13];
    const float* Whh_p = (const float*)d_in[14];
    const float* b_p   = (const float*)d_in[15];
    const float* W1 = (const float*)d_in[16];
    const float* a1 = (const float*)d_in[17];
    const float* W2 = (const float*)d_in[18];
    const float* a2 = (const float*)d_in[19];

    char* wsb = (char*)d_ws;
    size_t off = 0;
    auto alloc = [&](size_t bytes) -> char* {
        char* p = wsb + off;
        off += (bytes + 255) & ~(size_t)255;
        return p;
    };
    bf16*  Pfe = (bf16*)alloc((size_t)14541*400*2);
    bf16*  Pbe = (bf16*)alloc((size_t)14541*400*2);
    bf16*  Ppe = (bf16*)alloc((size_t)14541*400*2);
    bf16*  Pfr = (bf16*)alloc((size_t)237*400*2);
    bf16*  Pbr = (bf16*)alloc((size_t)237*400*2);
    bf16*  Ppr = (bf16*)alloc((size_t)237*400*2);
    float* WTf = (float*)alloc(40000*4);
    float* WTb = (float*)alloc(40000*4);
    float* WTp = (float*)alloc(40000*4);
    float* w1a = (float*)alloc(600*4);
    float* w1b = (float*)alloc(600*4);
    float* w2a = (float*)alloc(100*4);
    float* w2b = (float*)alloc(100*4);
    float* z   = (float*)alloc((size_t)2048*600*4);
    float* z2  = (float*)alloc((size_t)2048*100*4);

    float* dout  = (float*)d_out;
    float* out0  = dout;              // out2[:,0,:]  1024*600
    float* oatt  = dout + 614400;     // out_att      2048*600
    float* op0   = dout + 1843200;    // op2[:,0,:]   1024*100
    float* oatt2 = dout + 1945600;    // output_att   2048*100

    if (ws_size < off){
        k_sentinel<<<1,1,0,stream>>>(dout, (float)ws_size);
        return;
    }

    // K1: precompute input-projection tables (bf16), transposed recurrent weights, GAT score vectors
    k_proj<<<909, 256, 0, stream>>>(ent,  Wih_f, b_f, Pfe, 14541);
    k_proj<<<15,  256, 0, stream>>>(rel,  Wih_f, b_f, Pfr, 237);
    k_proj<<<909, 256, 0, stream>>>(ent,  Wih_b, b_b, Pbe, 14541);
    k_proj<<<15,  256, 0, stream>>>(rel,  Wih_b, b_b, Pbr, 237);
    k_proj<<<909, 256, 0, stream>>>(ent1, Wih_p, b_p, Ppe, 14541);
    k_proj<<<15,  256, 0, stream>>>(rel1, Wih_p, b_p, Ppr, 237);
    k_transpose<<<157, 256, 0, stream>>>(Whh_f, WTf);
    k_transpose<<<157, 256, 0, stream>>>(Whh_b, WTb);
    k_transpose<<<157, 256, 0, stream>>>(Whh_p, WTp);
    k_wvec<<<3, 256, 0, stream>>>(W1, a1, w1a, w1b, 600);
    k_wvec<<<1, 256, 0, stream>>>(W2, a2, w2a, w2b, 100);

    // K2: fused LSTMs + GAT attention per group of 40 samples
    k_fused<<<2048, 256, 0, stream>>>(bh, br, bt, Pfe, Pfr, Pbe, Pbr, Ppe, Ppr,
                                      WTf, WTb, WTp, w1a, w1b, w2a, w2b,
                                      z, z2, out0, op0);

    // K3: final GEMMs
    k_fgemm<<<dim3(128,3), 256, 16*600*4, stream>>>(z,  W1, oatt,  600);
    k_fgemm<<<dim3(128,1), 256, 16*100*4, stream>>>(z2, W2, oatt2, 100);
}

// Round 4
// 935.290 us; speedup vs baseline: 2.0092x; 2.0092x over previous
//
#include <hip/hip_runtime.h>
#include <hip/hip_bf16.h>
#include <cstdint>
#include <cstddef>
#include <cmath>

#define TID ((int)threadIdx.x)

typedef __attribute__((ext_vector_type(8))) short bf16x8;
typedef __attribute__((ext_vector_type(4))) float f32x4;
typedef __attribute__((ext_vector_type(4))) unsigned short us4;
typedef unsigned short ushort_t;

__device__ __forceinline__ float bfu2f(unsigned short u){
    unsigned int x = ((unsigned int)u) << 16; float f; __builtin_memcpy(&f, &x, 4); return f;
}
__device__ __forceinline__ unsigned short f2bu(float f){
    __hip_bfloat16 b = __float2bfloat16(f); unsigned short u; __builtin_memcpy(&u, &b, 2); return u;
}
__device__ __forceinline__ float sigmf(float x){
    x = fminf(fmaxf(x, -30.f), 30.f); return 1.0f/(1.0f + __expf(-x));
}
__device__ __forceinline__ float tanh_f(float x){
    x = fminf(fmaxf(x, -15.f), 15.f); float e = __expf(-2.f*x); return (1.f-e)/(1.f+e);
}

// ============ K1: one-shot prep: WihT (3x), Whh MFMA-A-fragment swizzle (3x), GAT W@a vectors ============
// Asw layout per LSTM: frag(mt,kt) = (mt*4+kt), 512 bf16 per frag: [lane][j].
// A_int row m = f*4+g  <->  Whh row g*100+f ;  k zero-padded 100->128.
__global__ __launch_bounds__(256) void k_prep(
    const float* __restrict__ Wih_f, const float* __restrict__ Wih_b, const float* __restrict__ Wih_p,
    const float* __restrict__ Whh_f, const float* __restrict__ Whh_b, const float* __restrict__ Whh_p,
    const float* __restrict__ W1, const float* __restrict__ a1,
    const float* __restrict__ W2, const float* __restrict__ a2,
    float* __restrict__ WihT3, unsigned short* __restrict__ Asw3,
    float* __restrict__ w1a, float* __restrict__ w1b,
    float* __restrict__ w2a, float* __restrict__ w2b)
{
    int bx = blockIdx.x;
    if (bx < 469){
        int e = bx*256 + TID;
        if (e < 120000){
            int l = e/40000, i = e - l*40000;
            int k = i/400, gg = i - k*400;
            const float* Ws = (l==0)?Wih_f:(l==1)?Wih_b:Wih_p;
            WihT3[e] = Ws[gg*100 + k];
        }
    } else if (bx < 1069){
        int e = (bx-469)*256 + TID;
        if (e < 153600){
            int l = e/51200, r = e - l*51200;
            int frag = r >> 9, q = r & 511;
            int lane = q >> 3, j = q & 7;
            int mt = frag >> 2, kt = frag & 3;
            int m = mt*16 + (lane & 15);
            int f = m >> 2, g = m & 3;
            int k = kt*32 + (lane >> 4)*8 + j;
            const float* Ws = (l==0)?Whh_f:(l==1)?Whh_b:Whh_p;
            float v = (k < 100) ? Ws[(g*100+f)*100 + k] : 0.f;
            Asw3[e] = f2bu(v);
        }
    } else {
        int idx = (bx-1069)*256 + TID;
        if (idx < 600){
            float x=0.f, y=0.f;
            for (int o=0;o<600;o++){ float w = W1[idx*600+o]; x += w*a1[o]; y += w*a1[600+o]; }
            w1a[idx]=x; w1b[idx]=y;
        } else if (idx < 700){
            int f = idx-600;
            float x=0.f, y=0.f;
            for (int o=0;o<100;o++){ float w = W2[f*100+o]; x += w*a2[o]; y += w*a2[100+o]; }
            w2a[f]=x; w2b[f]=y;
        }
    }
}

// ============ K2: P'[row][f*4+g] = (emb @ Wih^T + b), gate-interleaved, bf16 ============
// grid (909, 6): y = 0:ent/f 1:rel/f 2:ent/b 3:rel/b 4:ent1/p 5:rel1/p
__global__ __launch_bounds__(256) void k_proj(
    const float* __restrict__ ent, const float* __restrict__ rel,
    const float* __restrict__ ent1, const float* __restrict__ rel1,
    const float* __restrict__ b_f, const float* __restrict__ b_b, const float* __restrict__ b_p,
    const float* __restrict__ WihT3,
    unsigned short* __restrict__ Pfe, unsigned short* __restrict__ Pfr,
    unsigned short* __restrict__ Pbe, unsigned short* __restrict__ Pbr,
    unsigned short* __restrict__ Ppe, unsigned short* __restrict__ Ppr)
{
    int y = blockIdx.y;
    int l = y >> 1;
    int isrel = y & 1;
    int rows = isrel ? 237 : 14541;
    int r0 = blockIdx.x * 16;
    if (r0 >= rows) return;
    const float* emb  = isrel ? ((l==2)? rel1 : rel) : ((l==2)? ent1 : ent);
    const float* bias = (l==0)? b_f : (l==1)? b_b : b_p;
    const float* WT   = WihT3 + l*40000;
    unsigned short* P = (y==0)?Pfe:(y==1)?Pfr:(y==2)?Pbe:(y==3)?Pbr:(y==4)?Ppe:Ppr;

    __shared__ float el[16][100];
    for (int i=TID; i<1600; i+=256){
        int rr = i/100, k = i - rr*100;
        int rg = r0 + rr;
        el[rr][k] = (rg < rows) ? emb[rg*100 + k] : 0.f;
    }
    __syncthreads();
    for (int g=TID; g<400; g+=256){
        float b = bias[g];
        float acc[16];
#pragma unroll
        for (int r=0;r<16;r++) acc[r]=0.f;
        for (int k=0;k<100;k++){
            float w = WT[k*400 + g];        // coalesced across g
#pragma unroll
            for (int r=0;r<16;r++) acc[r] += el[r][k]*w;
        }
        int col = (g % 100)*4 + g/100;      // interleave gates: col = f*4 + gate
        for (int r=0;r<16;r++){
            int rg = r0 + r;
            if (rg < rows) P[(size_t)rg*400 + col] = f2bu(acc[r] + b);
        }
    }
}

// ============ K3: fused 3xLSTM (MFMA recurrence) + GAT attention, one block per 40-sample group ====
// GEMM per step: D[m=f*4+gate (400)][n=sample (48 pad)] = A_int(Whh swizzled) x B(h in HA).
// C-layout => lane owns cell (f = mt*4+quad, sample = nt*16+(lane&15)), regs = i,f,g,o gates.
__global__ __launch_bounds__(256, 2) void k_fused(
    const int* __restrict__ bh, const int* __restrict__ br, const int* __restrict__ bt,
    const unsigned short* __restrict__ Pfe, const unsigned short* __restrict__ Pfr,
    const unsigned short* __restrict__ Pbe, const unsigned short* __restrict__ Pbr,
    const unsigned short* __restrict__ Ppe, const unsigned short* __restrict__ Ppr,
    const unsigned short* __restrict__ Asw3,
    const float* __restrict__ w1a, const float* __restrict__ w1b,
    const float* __restrict__ w2a, const float* __restrict__ w2b,
    float* __restrict__ z, float* __restrict__ z2,
    float* __restrict__ out0, float* __restrict__ op0)
{
    __shared__ __align__(16) ushort_t HA[48][136];   // h staging (B operand), row-pad 136 for banks
    __shared__ __align__(16) ushort_t HO[40][600];   // BiLSTM out rows for attention
    __shared__ float sc1[40], tc1[40], sc2[40], tc2[40];
    __shared__ float att1[40], att2[40];
    __shared__ int sidx[3][40];

    int g = blockIdx.x;
    int m0 = g*40;
    if (TID < 40){
        sidx[0][TID] = bh[m0+TID];
        sidx[1][TID] = br[m0+TID];
        sidx[2][TID] = bt[m0+TID];
    }
    // zero HA (incl. k-pad cols: guards 0*NaN in MFMA)
    for (int i=TID; i<48*136; i+=256) ((ushort_t*)HA)[i] = 0;
    __syncthreads();

    int lane = TID & 63;
    int wid  = TID >> 6;
    int l15  = lane & 15;
    int quad = lane >> 4;
    int nmt  = (wid==0) ? 7 : 6;     // m-tiles per wave: wid + 4*i < 25
    bool doS0 = ((g & 1) == 0);
    int rrow = g >> 1;

    const unsigned short* PeA[3] = {Pfe, Pbe, Ppe};
    const unsigned short* PrA[3] = {Pfr, Pbr, Ppr};

    float c[21];

    for (int l=0; l<3; l++){
        const unsigned short* Aswl = Asw3 + l*51200;
        for (int t=0; t<3; t++){
            f32x4 acc[7][3];
#pragma unroll
            for (int i=0;i<7;i++)
#pragma unroll
                for (int nt=0;nt<3;nt++) acc[i][nt] = (f32x4){0.f,0.f,0.f,0.f};

            if (t > 0){
                bf16x8 bfr[3][4];
#pragma unroll
                for (int nt=0;nt<3;nt++)
#pragma unroll
                    for (int kt=0;kt<4;kt++)
                        bfr[nt][kt] = *(const bf16x8*)&HA[nt*16 + l15][kt*32 + quad*8];
#pragma unroll
                for (int i=0;i<7;i++){
                    if (i < nmt){
                        int mt = wid + 4*i;
                        bf16x8 af[4];
#pragma unroll
                        for (int kt=0;kt<4;kt++)
                            af[kt] = *(const bf16x8*)(Aswl + ((mt*4+kt)*64 + lane)*8);
#pragma unroll
                        for (int nt=0;nt<3;nt++)
#pragma unroll
                            for (int kt=0;kt<4;kt++)
                                acc[i][nt] = __builtin_amdgcn_mfma_f32_16x16x32_bf16(
                                    af[kt], bfr[nt][kt], acc[i][nt], 0, 0, 0);
                    }
                }
            }
            __syncthreads();   // all HA reads done before rewrite

            int p = (l==1) ? (2-t) : t;
            const unsigned short* tab = (p==1) ? PrA[l] : PeA[l];
#pragma unroll
            for (int i=0;i<7;i++){
                if (i < nmt){
                    int f = (wid + 4*i)*4 + quad;    // 0..99
#pragma unroll
                    for (int nt=0;nt<3;nt++){
                        int s = nt*16 + l15;
                        bool valid = s < 40;
                        int e = valid ? sidx[p][s] : 0;
                        us4 pv = *(const us4*)(tab + (size_t)e*400 + f*4);
                        f32x4 a4 = acc[i][nt];
                        float gi = a4[0] + bfu2f(pv[0]);
                        float gf = a4[1] + bfu2f(pv[1]);
                        float gg = a4[2] + bfu2f(pv[2]);
                        float go = a4[3] + bfu2f(pv[3]);
                        float cp = (t==0) ? 0.f : c[i*3+nt];
                        float cn = sigmf(gf)*cp + sigmf(gi)*tanh_f(gg);
                        float h  = sigmf(go)*tanh_f(cn);
                        c[i*3+nt] = cn;
                        if (valid){
                            HA[s][f] = f2bu(h);
                            if (l < 2){
                                int slot = (l==0) ? t*200 + f : (2-t)*200 + 100 + f;
                                HO[s][slot] = f2bu(h);
                                if (doS0 && s==0) out0[(size_t)rrow*600 + slot] = h;
                            } else {
                                if (doS0 && s==0 && t==2) op0[(size_t)rrow*100 + f] = h;
                            }
                        }
                    }
                }
            }
            __syncthreads();   // new h visible before next step
        }
    }
    // HA now holds final proc-LSTM h (bf16) in cols 0..99.

    // ---- attention score dots
    for (int n = wid; n < 40; n += 4){
        float a=0.f, b=0.f;
        for (int k=lane;k<600;k+=64){ float v=bfu2f(HO[n][k]); a += v*w1a[k]; b += v*w1b[k]; }
#pragma unroll
        for (int off=32; off>0; off>>=1){ a += __shfl_down(a,off,64); b += __shfl_down(b,off,64); }
        if (lane==0){ sc1[n]=a; tc1[n]=b; }
        float a2=0.f, b2=0.f;
        for (int k=lane;k<100;k+=64){ float v=bfu2f(HA[n][k]); a2 += v*w2a[k]; b2 += v*w2b[k]; }
#pragma unroll
        for (int off=32; off>0; off>>=1){ a2 += __shfl_down(a2,off,64); b2 += __shfl_down(b2,off,64); }
        if (lane==0){ sc2[n]=a2; tc2[n]=b2; }
    }
    __syncthreads();

    // ---- softmax(leaky_relu(s_n + t_0)) - MU, relu
    if (wid < 2){
        const float* sc = (wid==0)? sc1 : sc2;
        const float* tc = (wid==0)? tc1 : tc2;
        float* av       = (wid==0)? att1 : att2;
        float e = -1e30f;
        if (lane < 40){
            float x = sc[lane] + tc[0];
            e = (x > 0.f) ? x : 0.2f*x;
        }
        float mx = e;
#pragma unroll
        for (int off=32;off>0;off>>=1) mx = fmaxf(mx, __shfl_down(mx,off,64));
        mx = __shfl(mx, 0, 64);
        float pexp = (lane<40) ? __expf(e-mx) : 0.f;
        float sm = pexp;
#pragma unroll
        for (int off=32;off>0;off>>=1) sm += __shfl_down(sm,off,64);
        sm = __shfl(sm, 0, 64);
        if (lane < 40){
            float a = pexp/sm - 0.001f;
            av[lane] = (a > 0.f) ? a : 0.f;
        }
    }
    __syncthreads();

    // ---- z = sum_n att1[n]*HO[n][:600] ; z2 = sum_n att2[n]*HA[n][:100]
    for (int j=TID; j<600; j+=256){
        float acc = 0.f;
#pragma unroll
        for (int n=0;n<40;n++) acc += att1[n]*bfu2f(HO[n][j]);
        z[(size_t)g*600 + j] = acc;
    }
    for (int j=TID; j<100; j+=256){
        float acc = 0.f;
#pragma unroll
        for (int n=0;n<40;n++) acc += att2[n]*bfu2f(HA[n][j]);
        z2[(size_t)g*100 + j] = acc;
    }
}

// ============ K4: merged final GEMMs: y<3 -> oatt (dim 600 col-chunks), y==3 -> oatt2 (dim 100) ====
__global__ __launch_bounds__(256) void k_post(const float* __restrict__ z, const float* __restrict__ z2,
    const float* __restrict__ W1, const float* __restrict__ W2,
    float* __restrict__ oatt, float* __restrict__ oatt2)
{
    extern __shared__ float zl[];
    int y = blockIdx.y;
    const float* zz = (y==3)? z2 : z;
    const float* W  = (y==3)? W2 : W1;
    float* o        = (y==3)? oatt2 : oatt;
    int dim         = (y==3)? 100 : 600;
    int rb = blockIdx.x*16;
    for (int r=0;r<16;r++){
        for (int j=TID;j<dim;j+=256) zl[r*dim+j] = zz[(size_t)(rb+r)*dim + j];
    }
    __syncthreads();
    int cc = (y==3)? TID : y*256 + TID;
    if (cc < dim){
        float acc[16];
#pragma unroll
        for (int r=0;r<16;r++) acc[r]=0.f;
        for (int k=0;k<dim;k++){
            float w = W[(size_t)k*dim + cc];
#pragma unroll
            for (int r=0;r<16;r++) acc[r] += zl[r*dim+k]*w;
        }
        for (int r=0;r<16;r++) o[(size_t)(rb+r)*dim + cc] = acc[r];
    }
}

__global__ void k_sentinel(float* o, float v){ o[0] = v; }

extern "C" void kernel_launch(void* const* d_in, const int* in_sizes, int n_in,
                              void* d_out, int out_size, void* d_ws, size_t ws_size,
                              hipStream_t stream)
{
    const int*   bh   = (const int*)d_in[0];
    const int*   br   = (const int*)d_in[1];
    const int*   bt   = (const int*)d_in[2];
    const float* ent  = (const float*)d_in[3];
    const float* rel  = (const float*)d_in[4];
    const float* ent1 = (const float*)d_in[5];
    const float* rel1 = (const float*)d_in[6];
    const float* Wih_f = (const float*)d_in[7];
    const float* Whh_f = (const float*)d_in[8];
    const float* b_f   = (const float*)d_in[9];
    const float* Wih_b = (const float*)d_in[10];
    const float* Whh_b = (const float*)d_in[11];
    const float* b_b   = (const float*)d_in[12];
    const float* Wih_p = (const float*)d_in[13];
    const float* Whh_p = (const float*)d_in[14];
    const float* b_p   = (const float*)d_in[15];
    const float* W1 = (const float*)d_in[16];
    const float* a1 = (const float*)d_in[17];
    const float* W2 = (const float*)d_in[18];
    const float* a2 = (const float*)d_in[19];

    char* wsb = (char*)d_ws;
    size_t off = 0;
    auto alloc = [&](size_t bytes) -> char* {
        char* p = wsb + off;
        off += (bytes + 255) & ~(size_t)255;
        return p;
    };
    unsigned short* Pfe = (unsigned short*)alloc((size_t)14541*400*2);
    unsigned short* Pbe = (unsigned short*)alloc((size_t)14541*400*2);
    unsigned short* Ppe = (unsigned short*)alloc((size_t)14541*400*2);
    unsigned short* Pfr = (unsigned short*)alloc((size_t)237*400*2);
    unsigned short* Pbr = (unsigned short*)alloc((size_t)237*400*2);
    unsigned short* Ppr = (unsigned short*)alloc((size_t)237*400*2);
    float* WihT3 = (float*)alloc((size_t)120000*4);
    unsigned short* Asw3 = (unsigned short*)alloc((size_t)153600*2);
    float* w1a = (float*)alloc(600*4);
    float* w1b = (float*)alloc(600*4);
    float* w2a = (float*)alloc(100*4);
    float* w2b = (float*)alloc(100*4);
    float* z   = (float*)alloc((size_t)2048*600*4);
    float* z2  = (float*)alloc((size_t)2048*100*4);

    float* dout  = (float*)d_out;
    float* out0  = dout;              // out2[:,0,:]  1024*600
    float* oatt  = dout + 614400;     // out_att      2048*600
    float* op0   = dout + 1843200;    // op2[:,0,:]   1024*100
    float* oatt2 = dout + 1945600;    // output_att   2048*100

    if (ws_size < off){
        k_sentinel<<<1,1,0,stream>>>(dout, (float)ws_size);
        return;
    }

    k_prep<<<1072, 256, 0, stream>>>(Wih_f, Wih_b, Wih_p, Whh_f, Whh_b, Whh_p,
                                     W1, a1, W2, a2, WihT3, Asw3, w1a, w1b, w2a, w2b);

    k_proj<<<dim3(909,6), 256, 0, stream>>>(ent, rel, ent1, rel1, b_f, b_b, b_p,
                                            WihT3, Pfe, Pfr, Pbe, Pbr, Ppe, Ppr);

    k_fused<<<2048, 256, 0, stream>>>(bh, br, bt, Pfe, Pfr, Pbe, Pbr, Ppe, Ppr,
                                      Asw3, w1a, w1b, w2a, w2b, z, z2, out0, op0);

    k_post<<<dim3(128,4), 256, 16*600*4, stream>>>(z, z2, W1, W2, oatt, oatt2);
}

// Round 5
// 679.329 us; speedup vs baseline: 2.7662x; 1.3768x over previous
//
#include <hip/hip_runtime.h>
#include <hip/hip_bf16.h>
#include <cstdint>
#include <cstddef>
#include <cmath>

#define TID ((int)threadIdx.x)

typedef __attribute__((ext_vector_type(8))) short bf16x8;
typedef __attribute__((ext_vector_type(4))) float f32x4;
typedef __attribute__((ext_vector_type(4))) unsigned short us4;
typedef unsigned short ushort_t;

__device__ __forceinline__ float bfu2f(unsigned short u){
    unsigned int x = ((unsigned int)u) << 16; float f; __builtin_memcpy(&f, &x, 4); return f;
}
__device__ __forceinline__ unsigned short f2bu(float f){
    __hip_bfloat16 b = __float2bfloat16(f); unsigned short u; __builtin_memcpy(&u, &b, 2); return u;
}
// sigma(x) = 1/(1+exp(-x));  exp->inf => rcp->0 (saturates correctly, no clamp needed)
__device__ __forceinline__ float sigm(float x){
    return __builtin_amdgcn_rcpf(1.0f + __expf(-x));
}
// tanh(x) = 1 - 2/(1+exp(2x)); saturates correctly at +-inf
__device__ __forceinline__ float tanhx(float x){
    return 1.0f - 2.0f*__builtin_amdgcn_rcpf(1.0f + __expf(2.0f*x));
}
// raw barriers: do NOT drain vmcnt -> prefetched global loads stay in flight
__device__ __forceinline__ void bar_exec(){ asm volatile("s_barrier" ::: "memory"); }
__device__ __forceinline__ void bar_lds(){ asm volatile("s_waitcnt lgkmcnt(0)\n\ts_barrier" ::: "memory"); }

// ============ K1: prep: Whh A-frag swizzle (Asw3), Wih A-frag swizzle (Wsw3),
//                     gate-interleaved bias (bI3), GAT W@a vectors ============
// frag(mt,kt): 512 bf16, [lane][j]; m = mt*16+(lane&15) in interleaved space m=f*4+g;
// k = kt*32+(lane>>4)*8+j, zero-padded 100->128.
__global__ __launch_bounds__(256) void k_prep(
    const float* __restrict__ Wih_f, const float* __restrict__ Wih_b, const float* __restrict__ Wih_p,
    const float* __restrict__ Whh_f, const float* __restrict__ Whh_b, const float* __restrict__ Whh_p,
    const float* __restrict__ b_f, const float* __restrict__ b_b, const float* __restrict__ b_p,
    const float* __restrict__ W1, const float* __restrict__ a1,
    const float* __restrict__ W2, const float* __restrict__ a2,
    unsigned short* __restrict__ Asw3, unsigned short* __restrict__ Wsw3,
    float* __restrict__ bI3,
    float* __restrict__ w1a, float* __restrict__ w1b,
    float* __restrict__ w2a, float* __restrict__ w2b)
{
    int bx = blockIdx.x;
    if (bx < 1200){
        int isW = (bx >= 600) ? 1 : 0;
        int e = (bx - isW*600)*256 + TID;
        if (e < 153600){
            int l = e/51200, r = e - l*51200;
            int frag = r >> 9, q = r & 511;
            int lane = q >> 3, j = q & 7;
            int mt = frag >> 2, kt = frag & 3;
            int m = mt*16 + (lane & 15);
            int f = m >> 2, gg = m & 3;
            int k = kt*32 + (lane >> 4)*8 + j;
            const float* Ws = isW ? ((l==0)?Wih_f:(l==1)?Wih_b:Wih_p)
                                  : ((l==0)?Whh_f:(l==1)?Whh_b:Whh_p);
            float v = (k < 100) ? Ws[(gg*100+f)*100 + k] : 0.f;
            (isW ? Wsw3 : Asw3)[e] = f2bu(v);
        }
    } else if (bx == 1203){
        for (int e=TID; e<1200; e+=256){
            int l = e/400, m = e - l*400;
            int f = m >> 2, gg = m & 3;
            const float* bb = (l==0)?b_f:(l==1)?b_b:b_p;
            bI3[e] = bb[gg*100+f];
        }
    } else {
        int idx = (bx-1200)*256 + TID;
        if (idx < 600){
            float x=0.f, y=0.f;
            for (int o=0;o<600;o++){ float w = W1[idx*600+o]; x += w*a1[o]; y += w*a1[600+o]; }
            w1a[idx]=x; w1b[idx]=y;
        } else if (idx < 700){
            int f = idx-600;
            float x=0.f, y=0.f;
            for (int o=0;o<100;o++){ float w = W2[f*100+o]; x += w*a2[o]; y += w*a2[100+o]; }
            w2a[f]=x; w2b[f]=y;
        }
    }
}

// ============ K2: MFMA input projection: P'[row][f*4+g] = emb@Wih^T + b (bf16) ============
// grid (228, 6): y = 0:ent/f 1:rel/f 2:ent/b 3:rel/b 4:ent1/p 5:rel1/p. 64 rows/block.
__global__ __launch_bounds__(256) void k_projm(
    const float* __restrict__ ent, const float* __restrict__ rel,
    const float* __restrict__ ent1, const float* __restrict__ rel1,
    const unsigned short* __restrict__ Wsw3, const float* __restrict__ bI3,
    unsigned short* __restrict__ Pfe, unsigned short* __restrict__ Pfr,
    unsigned short* __restrict__ Pbe, unsigned short* __restrict__ Pbr,
    unsigned short* __restrict__ Ppe, unsigned short* __restrict__ Ppr)
{
    int y = blockIdx.y;
    int l = y >> 1;
    int isrel = y & 1;
    int rows = isrel ? 237 : 14541;
    int r0 = blockIdx.x * 64;
    if (r0 >= rows) return;
    const float* emb  = isrel ? ((l==2)? rel1 : rel) : ((l==2)? ent1 : ent);
    unsigned short* P = (y==0)?Pfe:(y==1)?Pfr:(y==2)?Pbe:(y==3)?Pbr:(y==4)?Ppe:Ppr;
    const unsigned short* A = Wsw3 + l*51200;
    const float* bI = bI3 + l*400;

    __shared__ __align__(16) ushort_t EB[64][136];
    for (int idx=TID; idx<64*128; idx+=256){
        int r = idx >> 7, k = idx & 127;
        int rg = r0 + r;
        float v = (rg < rows && k < 100) ? emb[rg*100 + k] : 0.f;
        EB[r][k] = f2bu(v);
    }
    __syncthreads();

    int lane = TID & 63, w = TID >> 6, l15 = lane & 15, quad = lane >> 4;
    int rg = r0 + w*16 + l15;
    bf16x8 bfr[4];
#pragma unroll
    for (int kt=0;kt<4;kt++) bfr[kt] = *(const bf16x8*)&EB[w*16 + l15][kt*32 + quad*8];

    for (int mt=0; mt<25; mt++){
        f32x4 acc = (f32x4){0.f,0.f,0.f,0.f};
#pragma unroll
        for (int kt=0;kt<4;kt++){
            bf16x8 af = *(const bf16x8*)(A + ((mt*4+kt)*64 + lane)*8);
            acc = __builtin_amdgcn_mfma_f32_16x16x32_bf16(af, bfr[kt], acc, 0, 0, 0);
        }
        f32x4 bv = *(const f32x4*)(bI + mt*16 + quad*4);
        us4 o;
#pragma unroll
        for (int r=0;r<4;r++) o[r] = f2bu(acc[r] + bv[r]);
        if (rg < rows) *(us4*)(P + (size_t)rg*400 + mt*16 + quad*4) = o;
    }
}

// ============ K3: fused 3xLSTM (MFMA recurrence, pipelined P gathers) + GAT ============
__global__ __launch_bounds__(256, 2) void k_fused(
    const int* __restrict__ bh, const int* __restrict__ br, const int* __restrict__ bt,
    const unsigned short* __restrict__ Pfe, const unsigned short* __restrict__ Pfr,
    const unsigned short* __restrict__ Pbe, const unsigned short* __restrict__ Pbr,
    const unsigned short* __restrict__ Ppe, const unsigned short* __restrict__ Ppr,
    const unsigned short* __restrict__ Asw3,
    const float* __restrict__ w1a, const float* __restrict__ w1b,
    const float* __restrict__ w2a, const float* __restrict__ w2b,
    float* __restrict__ z, float* __restrict__ z2,
    float* __restrict__ out0, float* __restrict__ op0)
{
    __shared__ __align__(16) ushort_t HA[48][136];   // h staging (B operand)
    __shared__ __align__(16) ushort_t HO[40][600];   // BiLSTM out rows for attention
    __shared__ float sc1[40], tc1[40], sc2[40], tc2[40];
    __shared__ float att1[40], att2[40];
    __shared__ int sidx[3][40];

    int g = blockIdx.x;
    int m0 = g*40;
    if (TID < 40){
        sidx[0][TID] = bh[m0+TID];
        sidx[1][TID] = br[m0+TID];
        sidx[2][TID] = bt[m0+TID];
    }
    for (int i=TID; i<48*136; i+=256) ((ushort_t*)HA)[i] = 0;
    __syncthreads();

    int lane = TID & 63;
    int wid  = TID >> 6;
    int l15  = lane & 15;
    int quad = lane >> 4;
    int nmt  = (wid==0) ? 7 : 6;          // m-tiles: wid + 4*i < 25
    bool doS0 = ((g & 1) == 0);
    int rrow = g >> 1;
    int s2i = (32 + l15 < 40) ? (32 + l15) : 0;   // clamped nt=2 sample index

    const unsigned short* PeA[3] = {Pfe, Pbe, Ppe};
    const unsigned short* PrA[3] = {Pfr, Pbr, Ppr};

    float c[21];
    us4 pvC[4][3], pvN[4][3];
    int eC0, eC1, eC2, eN0, eN1, eN2;

    // prologue prefetch for step (l=0,t=0): p=0 -> Pfe
    {
        eN0 = sidx[0][l15]; eN1 = sidx[0][16+l15]; eN2 = sidx[0][s2i];
#pragma unroll
        for (int i=0;i<4;i++){
            int f4 = ((wid + 4*i)*4 + quad)*4;
            pvN[i][0] = *(const us4*)(Pfe + (size_t)eN0*400 + f4);
            pvN[i][1] = *(const us4*)(Pfe + (size_t)eN1*400 + f4);
            pvN[i][2] = *(const us4*)(Pfe + (size_t)eN2*400 + f4);
        }
    }

    for (int l=0; l<3; l++){
        const unsigned short* Aswl = Asw3 + l*51200;
        for (int t=0; t<3; t++){
            // rotate prefetch buffers
#pragma unroll
            for (int i=0;i<4;i++){ pvC[i][0]=pvN[i][0]; pvC[i][1]=pvN[i][1]; pvC[i][2]=pvN[i][2]; }
            eC0 = eN0; eC1 = eN1; eC2 = eN2;

            f32x4 acc[7][3];
#pragma unroll
            for (int i=0;i<7;i++)
#pragma unroll
                for (int nt=0;nt<3;nt++) acc[i][nt] = (f32x4){0.f,0.f,0.f,0.f};

            if (t > 0){
                bf16x8 bfr[3][4];
#pragma unroll
                for (int nt=0;nt<3;nt++)
#pragma unroll
                    for (int kt=0;kt<4;kt++)
                        bfr[nt][kt] = *(const bf16x8*)&HA[nt*16 + l15][kt*32 + quad*8];
#pragma unroll
                for (int i=0;i<7;i++){
                    if (i < nmt){
                        int mt = wid + 4*i;
                        bf16x8 af[4];
#pragma unroll
                        for (int kt=0;kt<4;kt++)
                            af[kt] = *(const bf16x8*)(Aswl + ((mt*4+kt)*64 + lane)*8);
#pragma unroll
                        for (int nt=0;nt<3;nt++)
#pragma unroll
                            for (int kt=0;kt<4;kt++)
                                acc[i][nt] = __builtin_amdgcn_mfma_f32_16x16x32_bf16(
                                    af[kt], bfr[nt][kt], acc[i][nt], 0, 0, 0);
                    }
                }
            }

            // prefetch next step's near-tile P gathers (stays in flight across raw barriers)
            if (!(l==2 && t==2)){
                int ln = (t==2) ? l+1 : l;
                int tn = (t==2) ? 0 : t+1;
                int pn = (ln==1) ? (2-tn) : tn;
                const unsigned short* tabn = (pn==1) ? PrA[ln] : PeA[ln];
                eN0 = sidx[pn][l15]; eN1 = sidx[pn][16+l15]; eN2 = sidx[pn][s2i];
#pragma unroll
                for (int i=0;i<4;i++){
                    int f4 = ((wid + 4*i)*4 + quad)*4;
                    pvN[i][0] = *(const us4*)(tabn + (size_t)eN0*400 + f4);
                    pvN[i][1] = *(const us4*)(tabn + (size_t)eN1*400 + f4);
                    pvN[i][2] = *(const us4*)(tabn + (size_t)eN2*400 + f4);
                }
            }

            bar_exec();   // HA reads done (waited by MFMA use) before rewrite; no vmcnt drain

            // far tiles (i=4..6): direct loads, covered by i<4 cell math
            int p = (l==1) ? (2-t) : t;
            const unsigned short* tab = (p==1) ? PrA[l] : PeA[l];
            us4 pvD[3][3];
#pragma unroll
            for (int i=4;i<7;i++){
                if (i < nmt){
                    int f4 = ((wid + 4*i)*4 + quad)*4;
                    pvD[i-4][0] = *(const us4*)(tab + (size_t)eC0*400 + f4);
                    pvD[i-4][1] = *(const us4*)(tab + (size_t)eC1*400 + f4);
                    pvD[i-4][2] = *(const us4*)(tab + (size_t)eC2*400 + f4);
                }
            }
            int wslotbase = (l==0) ? t*200 : (2-t)*200 + 100;   // only used for l<2
#pragma unroll
            for (int i=0;i<7;i++){
                if (i < nmt){
                    int f = (wid + 4*i)*4 + quad;    // 0..99
#pragma unroll
                    for (int nt=0;nt<3;nt++){
                        int s = nt*16 + l15;
                        bool valid = (nt < 2) || (l15 < 8);
                        us4 pv = (i < 4) ? pvC[i][nt] : pvD[i-4][nt];
                        f32x4 a4 = acc[i][nt];
                        float gi = a4[0] + bfu2f(pv[0]);
                        float gf = a4[1] + bfu2f(pv[1]);
                        float gg = a4[2] + bfu2f(pv[2]);
                        float go = a4[3] + bfu2f(pv[3]);
                        float cp = (t==0) ? 0.f : c[i*3+nt];
                        float cn = sigm(gf)*cp + sigm(gi)*tanhx(gg);
                        float h  = sigm(go)*tanhx(cn);
                        c[i*3+nt] = cn;
                        if (valid){
                            if (t < 2 || l == 2) HA[s][f] = f2bu(h);
                            if (l < 2){
                                int slot = wslotbase + f;
                                HO[s][slot] = f2bu(h);
                                if (doS0 && s==0) out0[(size_t)rrow*600 + slot] = h;
                            } else if (t==2 && doS0 && s==0){
                                op0[(size_t)rrow*100 + f] = h;
                            }
                        }
                    }
                }
            }

            bar_lds();    // drain ds_writes, barrier; no vmcnt drain
        }
    }
    // HA cols 0..99 now hold final proc-LSTM h.

    // ---- attention score dots
    for (int n = wid; n < 40; n += 4){
        float a=0.f, b=0.f;
        for (int k=lane;k<600;k+=64){ float v=bfu2f(HO[n][k]); a += v*w1a[k]; b += v*w1b[k]; }
#pragma unroll
        for (int off=32; off>0; off>>=1){ a += __shfl_down(a,off,64); b += __shfl_down(b,off,64); }
        if (lane==0){ sc1[n]=a; tc1[n]=b; }
        float a2=0.f, b2=0.f;
        for (int k=lane;k<100;k+=64){ float v=bfu2f(HA[n][k]); a2 += v*w2a[k]; b2 += v*w2b[k]; }
#pragma unroll
        for (int off=32; off>0; off>>=1){ a2 += __shfl_down(a2,off,64); b2 += __shfl_down(b2,off,64); }
        if (lane==0){ sc2[n]=a2; tc2[n]=b2; }
    }
    __syncthreads();

    // ---- softmax(leaky_relu(s_n + t_0)) - MU, relu
    if (wid < 2){
        const float* sc = (wid==0)? sc1 : sc2;
        const float* tc = (wid==0)? tc1 : tc2;
        float* av       = (wid==0)? att1 : att2;
        float e = -1e30f;
        if (lane < 40){
            float x = sc[lane] + tc[0];
            e = (x > 0.f) ? x : 0.2f*x;
        }
        float mx = e;
#pragma unroll
        for (int off=32;off>0;off>>=1) mx = fmaxf(mx, __shfl_down(mx,off,64));
        mx = __shfl(mx, 0, 64);
        float pexp = (lane<40) ? __expf(e-mx) : 0.f;
        float sm = pexp;
#pragma unroll
        for (int off=32;off>0;off>>=1) sm += __shfl_down(sm,off,64);
        sm = __shfl(sm, 0, 64);
        if (lane < 40){
            float a = pexp/sm - 0.001f;
            av[lane] = (a > 0.f) ? a : 0.f;
        }
    }
    __syncthreads();

    // ---- z = sum_n att1[n]*HO[n][:600] ; z2 = sum_n att2[n]*HA[n][:100]
    for (int j=TID; j<600; j+=256){
        float acc = 0.f;
#pragma unroll
        for (int n=0;n<40;n++) acc += att1[n]*bfu2f(HO[n][j]);
        z[(size_t)g*600 + j] = acc;
    }
    for (int j=TID; j<100; j+=256){
        float acc = 0.f;
#pragma unroll
        for (int n=0;n<40;n++) acc += att2[n]*bfu2f(HA[n][j]);
        z2[(size_t)g*100 + j] = acc;
    }
}

// ============ K4: merged final GEMMs: y<3 -> oatt (600 col-chunks), y==3 -> oatt2 (100) ====
__global__ __launch_bounds__(256) void k_post(const float* __restrict__ z, const float* __restrict__ z2,
    const float* __restrict__ W1, const float* __restrict__ W2,
    float* __restrict__ oatt, float* __restrict__ oatt2)
{
    extern __shared__ float zl[];
    int y = blockIdx.y;
    const float* zz = (y==3)? z2 : z;
    const float* W  = (y==3)? W2 : W1;
    float* o        = (y==3)? oatt2 : oatt;
    int dim         = (y==3)? 100 : 600;
    int rb = blockIdx.x*16;
    for (int r=0;r<16;r++){
        for (int j=TID;j<dim;j+=256) zl[r*dim+j] = zz[(size_t)(rb+r)*dim + j];
    }
    __syncthreads();
    int cc = (y==3)? TID : y*256 + TID;
    if (cc < dim){
        float acc[16];
#pragma unroll
        for (int r=0;r<16;r++) acc[r]=0.f;
        for (int k=0;k<dim;k++){
            float w = W[(size_t)k*dim + cc];
#pragma unroll
            for (int r=0;r<16;r++) acc[r] += zl[r*dim+k]*w;
        }
        for (int r=0;r<16;r++) o[(size_t)(rb+r)*dim + cc] = acc[r];
    }
}

__global__ void k_sentinel(float* o, float v){ o[0] = v; }

extern "C" void kernel_launch(void* const* d_in, const int* in_sizes, int n_in,
                              void* d_out, int out_size, void* d_ws, size_t ws_size,
                              hipStream_t stream)
{
    const int*   bh   = (const int*)d_in[0];
    const int*   br   = (const int*)d_in[1];
    const int*   bt   = (const int*)d_in[2];
    const float* ent  = (const float*)d_in[3];
    const float* rel  = (const float*)d_in[4];
    const float* ent1 = (const float*)d_in[5];
    const float* rel1 = (const float*)d_in[6];
    const float* Wih_f = (const float*)d_in[7];
    const float* Whh_f = (const float*)d_in[8];
    const float* b_f   = (const float*)d_in[9];
    const float* Wih_b = (const float*)d_in[10];
    const float* Whh_b = (const float*)d_in[11];
    const float* b_b   = (const float*)d_in[12];
    const float* Wih_p = (const float*)d_in[13];
    const float* Whh_p = (const float*)d_in[14];
    const float* b_p   = (const float*)d_in[15];
    const float* W1 = (const float*)d_in[16];
    const float* a1 = (const float*)d_in[17];
    const float* W2 = (const float*)d_in[18];
    const float* a2 = (const float*)d_in[19];

    char* wsb = (char*)d_ws;
    size_t off = 0;
    auto alloc = [&](size_t bytes) -> char* {
        char* p = wsb + off;
        off += (bytes + 255) & ~(size_t)255;
        return p;
    };
    unsigned short* Pfe = (unsigned short*)alloc((size_t)14541*400*2);
    unsigned short* Pbe = (unsigned short*)alloc((size_t)14541*400*2);
    unsigned short* Ppe = (unsigned short*)alloc((size_t)14541*400*2);
    unsigned short* Pfr = (unsigned short*)alloc((size_t)237*400*2);
    unsigned short* Pbr = (unsigned short*)alloc((size_t)237*400*2);
    unsigned short* Ppr = (unsigned short*)alloc((size_t)237*400*2);
    unsigned short* Asw3 = (unsigned short*)alloc((size_t)153600*2);
    unsigned short* Wsw3 = (unsigned short*)alloc((size_t)153600*2);
    float* bI3 = (float*)alloc(1200*4);
    float* w1a = (float*)alloc(600*4);
    float* w1b = (float*)alloc(600*4);
    float* w2a = (float*)alloc(100*4);
    float* w2b = (float*)alloc(100*4);
    float* z   = (float*)alloc((size_t)2048*600*4);
    float* z2  = (float*)alloc((size_t)2048*100*4);

    float* dout  = (float*)d_out;
    float* out0  = dout;              // out2[:,0,:]  1024*600
    float* oatt  = dout + 614400;     // out_att      2048*600
    float* op0   = dout + 1843200;    // op2[:,0,:]   1024*100
    float* oatt2 = dout + 1945600;    // output_att   2048*100

    if (ws_size < off){
        k_sentinel<<<1,1,0,stream>>>(dout, (float)ws_size);
        return;
    }

    k_prep<<<1204, 256, 0, stream>>>(Wih_f, Wih_b, Wih_p, Whh_f, Whh_b, Whh_p,
                                     b_f, b_b, b_p, W1, a1, W2, a2,
                                     Asw3, Wsw3, bI3, w1a, w1b, w2a, w2b);

    k_projm<<<dim3(228,6), 256, 0, stream>>>(ent, rel, ent1, rel1, Wsw3, bI3,
                                             Pfe, Pfr, Pbe, Pbr, Ppe, Ppr);

    k_fused<<<2048, 256, 0, stream>>>(bh, br, bt, Pfe, Pfr, Pbe, Pbr, Ppe, Ppr,
                                      Asw3, w1a, w1b, w2a, w2b, z, z2, out0, op0);

    k_post<<<dim3(128,4), 256, 16*600*4, stream>>>(z, z2, W1, W2, oatt, oatt2);
}

// Round 6
// 594.190 us; speedup vs baseline: 3.1626x; 1.1433x over previous
//
#include <hip/hip_runtime.h>
#include <hip/hip_bf16.h>
#include <cstdint>
#include <cstddef>
#include <cmath>

#define TID ((int)threadIdx.x)

typedef __attribute__((ext_vector_type(8))) short bf16x8;
typedef __attribute__((ext_vector_type(4))) float f32x4;
typedef __attribute__((ext_vector_type(4))) unsigned short us4;
typedef unsigned short ushort_t;

__device__ __forceinline__ float bfu2f(unsigned short u){
    unsigned int x = ((unsigned int)u) << 16; float f; __builtin_memcpy(&f, &x, 4); return f;
}
__device__ __forceinline__ unsigned short f2bu(float f){
    __hip_bfloat16 b = __float2bfloat16(f); unsigned short u; __builtin_memcpy(&u, &b, 2); return u;
}
// sigma(x) = 1/(1+exp(-x)); exp->inf => rcp->0 (saturates correctly)
__device__ __forceinline__ float sigm(float x){
    return __builtin_amdgcn_rcpf(1.0f + __expf(-x));
}
// tanh(x) = 1 - 2/(1+exp(2x)); saturates correctly
__device__ __forceinline__ float tanhx(float x){
    return 1.0f - 2.0f*__builtin_amdgcn_rcpf(1.0f + __expf(2.0f*x));
}
// raw barrier + LDS drain only: does NOT drain vmcnt -> global prefetches stay in flight
__device__ __forceinline__ void bar_lds(){ asm volatile("s_waitcnt lgkmcnt(0)\n\ts_barrier" ::: "memory"); }

// ============ K1: prep: Whh A-frag swizzle (Asw3), Wih A-frag swizzle (Wsw3),
//                  gate-interleaved bias (bI3), GAT W@a vectors (coalesced) ============
__global__ __launch_bounds__(256) void k_prep(
    const float* __restrict__ Wih_f, const float* __restrict__ Wih_b, const float* __restrict__ Wih_p,
    const float* __restrict__ Whh_f, const float* __restrict__ Whh_b, const float* __restrict__ Whh_p,
    const float* __restrict__ b_f, const float* __restrict__ b_b, const float* __restrict__ b_p,
    const float* __restrict__ W1, const float* __restrict__ a1,
    const float* __restrict__ W2, const float* __restrict__ a2,
    unsigned short* __restrict__ Asw3, unsigned short* __restrict__ Wsw3,
    float* __restrict__ bI3,
    float* __restrict__ w1a, float* __restrict__ w1b,
    float* __restrict__ w2a, float* __restrict__ w2b)
{
    int bx = blockIdx.x;
    if (bx < 1200){
        int isW = (bx >= 600) ? 1 : 0;
        int e = (bx - isW*600)*256 + TID;     // 600*256 = 153600 exactly
        int l = e/51200, r = e - l*51200;
        int frag = r >> 9, q = r & 511;
        int lanep = q >> 3, j = q & 7;
        int mt = frag >> 2, kt = frag & 3;
        int m = mt*16 + (lanep & 15);
        int f = m >> 2, gg = m & 3;
        int k = kt*32 + (lanep >> 4)*8 + j;
        const float* Ws = isW ? ((l==0)?Wih_f:(l==1)?Wih_b:Wih_p)
                              : ((l==0)?Whh_f:(l==1)?Whh_b:Whh_p);
        float v = (k < 100) ? Ws[(gg*100+f)*100 + k] : 0.f;
        (isW ? Wsw3 : Asw3)[e] = f2bu(v);
    } else if (bx == 1200){
        for (int e=TID; e<1200; e+=256){
            int l = e/400, m = e - l*400;
            int f = m >> 2, gg = m & 3;
            const float* bb = (l==0)?b_f:(l==1)?b_b:b_p;
            bI3[e] = bb[gg*100+f];
        }
    } else {
        int lane = TID & 63, w = TID >> 6;
        int r = (bx - 1201)*4 + w;            // 0..699
        if (r < 600){
            float x=0.f, y=0.f;
            for (int k=lane;k<600;k+=64){ float wv=W1[r*600+k]; x+=wv*a1[k]; y+=wv*a1[600+k]; }
#pragma unroll
            for (int off=32;off>0;off>>=1){ x+=__shfl_down(x,off,64); y+=__shfl_down(y,off,64); }
            if (lane==0){ w1a[r]=x; w1b[r]=y; }
        } else if (r < 700){
            int f = r-600;
            float x=0.f, y=0.f;
            for (int k=lane;k<100;k+=64){ float wv=W2[f*100+k]; x+=wv*a2[k]; y+=wv*a2[100+k]; }
#pragma unroll
            for (int off=32;off>0;off>>=1){ x+=__shfl_down(x,off,64); y+=__shfl_down(y,off,64); }
            if (lane==0){ w2a[f]=x; w2b[f]=y; }
        }
    }
}

// ============ K2: MFMA input projection: P'[row][f*4+g] = emb@Wih^T + b (bf16) ============
// grid (228, 6): y = 0:ent/f 1:rel/f 2:ent/b 3:rel/b 4:ent1/p 5:rel1/p. 64 rows/block.
__global__ __launch_bounds__(256) void k_projm(
    const float* __restrict__ ent, const float* __restrict__ rel,
    const float* __restrict__ ent1, const float* __restrict__ rel1,
    const unsigned short* __restrict__ Wsw3, const float* __restrict__ bI3,
    unsigned short* __restrict__ Pfe, unsigned short* __restrict__ Pfr,
    unsigned short* __restrict__ Pbe, unsigned short* __restrict__ Pbr,
    unsigned short* __restrict__ Ppe, unsigned short* __restrict__ Ppr)
{
    int y = blockIdx.y;
    int l = y >> 1;
    int isrel = y & 1;
    int rows = isrel ? 237 : 14541;
    int r0 = blockIdx.x * 64;
    if (r0 >= rows) return;
    const float* emb  = isrel ? ((l==2)? rel1 : rel) : ((l==2)? ent1 : ent);
    unsigned short* P = (y==0)?Pfe:(y==1)?Pfr:(y==2)?Pbe:(y==3)?Pbr:(y==4)?Ppe:Ppr;
    const unsigned short* A = Wsw3 + l*51200;
    const float* bI = bI3 + l*400;

    __shared__ __align__(16) ushort_t EB[64][136];
    for (int idx=TID; idx<64*128; idx+=256){
        int r = idx >> 7, k = idx & 127;
        int rg = r0 + r;
        float v = (rg < rows && k < 100) ? emb[rg*100 + k] : 0.f;
        EB[r][k] = f2bu(v);
    }
    __syncthreads();

    int lane = TID & 63, w = TID >> 6, l15 = lane & 15, quad = lane >> 4;
    int rg = r0 + w*16 + l15;
    bf16x8 bfr[4];
#pragma unroll
    for (int kt=0;kt<4;kt++) bfr[kt] = *(const bf16x8*)&EB[w*16 + l15][kt*32 + quad*8];

    for (int mt=0; mt<25; mt++){
        f32x4 acc = (f32x4){0.f,0.f,0.f,0.f};
#pragma unroll
        for (int kt=0;kt<4;kt++){
            bf16x8 af = *(const bf16x8*)(A + ((mt*4+kt)*64 + lane)*8);
            acc = __builtin_amdgcn_mfma_f32_16x16x32_bf16(af, bfr[kt], acc, 0, 0, 0);
        }
        f32x4 bv = *(const f32x4*)(bI + mt*16 + quad*4);
        us4 o;
#pragma unroll
        for (int r=0;r<4;r++) o[r] = f2bu(acc[r] + bv[r]);
        if (rg < rows) *(us4*)(P + (size_t)rg*400 + mt*16 + quad*4) = o;
    }
}

// ============ K3: fused 3xLSTM (MFMA, per-tile fused cell math, no spills) + GAT ============
__global__ __launch_bounds__(256, 2) void k_fused(
    const int* __restrict__ bh, const int* __restrict__ br, const int* __restrict__ bt,
    const unsigned short* __restrict__ Pfe, const unsigned short* __restrict__ Pfr,
    const unsigned short* __restrict__ Pbe, const unsigned short* __restrict__ Pbr,
    const unsigned short* __restrict__ Ppe, const unsigned short* __restrict__ Ppr,
    const unsigned short* __restrict__ Asw3,
    const float* __restrict__ w1a, const float* __restrict__ w1b,
    const float* __restrict__ w2a, const float* __restrict__ w2b,
    float* __restrict__ z, float* __restrict__ z2,
    float* __restrict__ out0, float* __restrict__ op0)
{
    __shared__ __align__(16) ushort_t HA[48][136];   // h staging (B operand)
    __shared__ __align__(16) ushort_t HO[40][600];   // BiLSTM out rows for attention
    __shared__ float sc1[40], tc1[40], sc2[40], tc2[40];
    __shared__ float att1[40], att2[40];
    __shared__ int sidx[3][40];

    int g = blockIdx.x;
    int m0 = g*40;
    if (TID < 40){
        sidx[0][TID] = bh[m0+TID];
        sidx[1][TID] = br[m0+TID];
        sidx[2][TID] = bt[m0+TID];
    }
    for (int i=TID; i<48*136; i+=256) ((ushort_t*)HA)[i] = 0;
    __syncthreads();

    int lane = TID & 63;
    int wid  = TID >> 6;
    int l15  = lane & 15;
    int quad = lane >> 4;
    int nmt  = (wid==0) ? 7 : 6;          // m-tiles: wid + 4*i < 25
    bool doS0 = ((g & 1) == 0);
    int rrow = g >> 1;
    int s2i = (l15 < 8) ? (32 + l15) : 0; // clamped nt=2 sample index

    const unsigned short* PeA[3] = {Pfe, Pbe, Ppe};
    const unsigned short* PrA[3] = {Pfr, Pbr, Ppr};

    float c[21];
    us4 pv[7][3];

    // prologue prefetch for step (l=0,t=0): p=0 -> Pfe
    {
        int e0 = sidx[0][l15], e1 = sidx[0][16+l15], e2 = sidx[0][s2i];
#pragma unroll
        for (int i=0;i<7;i++){
            if (i < nmt){
                int f4 = ((wid + 4*i)*4 + quad)*4;
                pv[i][0] = *(const us4*)(Pfe + (size_t)e0*400 + f4);
                pv[i][1] = *(const us4*)(Pfe + (size_t)e1*400 + f4);
                pv[i][2] = *(const us4*)(Pfe + (size_t)e2*400 + f4);
            }
        }
    }

    for (int l=0; l<3; l++){
        const unsigned short* Aswl = Asw3 + l*51200;
        for (int t=0; t<3; t++){
            bf16x8 bfr[3][4];
            if (t > 0){
#pragma unroll
                for (int nt=0;nt<3;nt++)
#pragma unroll
                    for (int kt=0;kt<4;kt++)
                        bfr[nt][kt] = *(const bf16x8*)&HA[nt*16 + l15][kt*32 + quad*8];
                bar_lds();   // all waves' HA reads landed in regs before any HA rewrite
            }

            int wslotbase = (l==0) ? t*200 : (2-t)*200 + 100;   // used only for l<2
#pragma unroll
            for (int i=0;i<7;i++){
                if (i < nmt){
                    f32x4 acc3[3];
#pragma unroll
                    for (int nt=0;nt<3;nt++) acc3[nt] = (f32x4){0.f,0.f,0.f,0.f};
                    if (t > 0){
                        int mt = wid + 4*i;
#pragma unroll
                        for (int kt=0;kt<4;kt++){
                            bf16x8 af = *(const bf16x8*)(Aswl + ((mt*4+kt)*64 + lane)*8);
#pragma unroll
                            for (int nt=0;nt<3;nt++)
                                acc3[nt] = __builtin_amdgcn_mfma_f32_16x16x32_bf16(
                                    af, bfr[nt][kt], acc3[nt], 0, 0, 0);
                        }
                    }
                    int f = (wid + 4*i)*4 + quad;    // 0..99
#pragma unroll
                    for (int nt=0;nt<3;nt++){
                        int s = nt*16 + l15;
                        bool valid = (nt < 2) || (l15 < 8);
                        us4 p4 = pv[i][nt];
                        f32x4 a4 = acc3[nt];
                        float gi = a4[0] + bfu2f(p4[0]);
                        float gf = a4[1] + bfu2f(p4[1]);
                        float gg = a4[2] + bfu2f(p4[2]);
                        float go = a4[3] + bfu2f(p4[3]);
                        float cp = (t==0) ? 0.f : c[i*3+nt];
                        float cn = sigm(gf)*cp + sigm(gi)*tanhx(gg);
                        float h  = sigm(go)*tanhx(cn);
                        c[i*3+nt] = cn;
                        if (valid){
                            if (t < 2 || l == 2) HA[s][f] = f2bu(h);
                            if (l < 2){
                                int slot = wslotbase + f;
                                HO[s][slot] = f2bu(h);
                                if (doS0 && s==0) out0[(size_t)rrow*600 + slot] = h;
                            } else if (t==2 && doS0 && s==0){
                                op0[(size_t)rrow*100 + f] = h;
                            }
                        }
                    }
                }
            }

            // prefetch next step's P gathers into the now-free pv regs
            if (!(l==2 && t==2)){
                int ln = (t==2) ? l+1 : l;
                int tn = (t==2) ? 0 : t+1;
                int pn = (ln==1) ? (2-tn) : tn;
                const unsigned short* tabn = (pn==1) ? PrA[ln] : PeA[ln];
                int e0 = sidx[pn][l15], e1 = sidx[pn][16+l15], e2 = sidx[pn][s2i];
#pragma unroll
                for (int i=0;i<7;i++){
                    if (i < nmt){
                        int f4 = ((wid + 4*i)*4 + quad)*4;
                        pv[i][0] = *(const us4*)(tabn + (size_t)e0*400 + f4);
                        pv[i][1] = *(const us4*)(tabn + (size_t)e1*400 + f4);
                        pv[i][2] = *(const us4*)(tabn + (size_t)e2*400 + f4);
                    }
                }
            }

            bar_lds();   // drain HA/HO ds_writes + barrier; prefetches stay in flight
        }
    }
    // HA cols 0..99 now hold final proc-LSTM h.

    // ---- attention score dots
    for (int n = wid; n < 40; n += 4){
        float a=0.f, b=0.f;
        for (int k=lane;k<600;k+=64){ float v=bfu2f(HO[n][k]); a += v*w1a[k]; b += v*w1b[k]; }
#pragma unroll
        for (int off=32; off>0; off>>=1){ a += __shfl_down(a,off,64); b += __shfl_down(b,off,64); }
        if (lane==0){ sc1[n]=a; tc1[n]=b; }
        float a2=0.f, b2=0.f;
        for (int k=lane;k<100;k+=64){ float v=bfu2f(HA[n][k]); a2 += v*w2a[k]; b2 += v*w2b[k]; }
#pragma unroll
        for (int off=32; off>0; off>>=1){ a2 += __shfl_down(a2,off,64); b2 += __shfl_down(b2,off,64); }
        if (lane==0){ sc2[n]=a2; tc2[n]=b2; }
    }
    __syncthreads();

    // ---- softmax(leaky_relu(s_n + t_0)) - MU, relu
    if (wid < 2){
        const float* sc = (wid==0)? sc1 : sc2;
        const float* tc = (wid==0)? tc1 : tc2;
        float* av       = (wid==0)? att1 : att2;
        float e = -1e30f;
        if (lane < 40){
            float x = sc[lane] + tc[0];
            e = (x > 0.f) ? x : 0.2f*x;
        }
        float mx = e;
#pragma unroll
        for (int off=32;off>0;off>>=1) mx = fmaxf(mx, __shfl_down(mx,off,64));
        mx = __shfl(mx, 0, 64);
        float pexp = (lane<40) ? __expf(e-mx) : 0.f;
        float sm = pexp;
#pragma unroll
        for (int off=32;off>0;off>>=1) sm += __shfl_down(sm,off,64);
        sm = __shfl(sm, 0, 64);
        if (lane < 40){
            float a = pexp/sm - 0.001f;
            av[lane] = (a > 0.f) ? a : 0.f;
        }
    }
    __syncthreads();

    // ---- z = sum_n att1[n]*HO[n][:600] ; z2 = sum_n att2[n]*HA[n][:100]
    for (int j=TID; j<600; j+=256){
        float acc = 0.f;
#pragma unroll
        for (int n=0;n<40;n++) acc += att1[n]*bfu2f(HO[n][j]);
        z[(size_t)g*600 + j] = acc;
    }
    for (int j=TID; j<100; j+=256){
        float acc = 0.f;
#pragma unroll
        for (int n=0;n<40;n++) acc += att2[n]*bfu2f(HA[n][j]);
        z2[(size_t)g*100 + j] = acc;
    }
}

// ============ K4: merged final GEMMs: y<3 -> oatt (600 col-chunks), y==3 -> oatt2 (100) ====
__global__ __launch_bounds__(256) void k_post(const float* __restrict__ z, const float* __restrict__ z2,
    const float* __restrict__ W1, const float* __restrict__ W2,
    float* __restrict__ oatt, float* __restrict__ oatt2)
{
    extern __shared__ float zl[];
    int y = blockIdx.y;
    const float* zz = (y==3)? z2 : z;
    const float* W  = (y==3)? W2 : W1;
    float* o        = (y==3)? oatt2 : oatt;
    int dim         = (y==3)? 100 : 600;
    int rb = blockIdx.x*16;
    for (int r=0;r<16;r++){
        for (int j=TID;j<dim;j+=256) zl[r*dim+j] = zz[(size_t)(rb+r)*dim + j];
    }
    __syncthreads();
    int cc = (y==3)? TID : y*256 + TID;
    if (cc < dim){
        float acc[16];
#pragma unroll
        for (int r=0;r<16;r++) acc[r]=0.f;
        for (int k=0;k<dim;k++){
            float w = W[(size_t)k*dim + cc];
#pragma unroll
            for (int r=0;r<16;r++) acc[r] += zl[r*dim+k]*w;
        }
        for (int r=0;r<16;r++) o[(size_t)(rb+r)*dim + cc] = acc[r];
    }
}

__global__ void k_sentinel(float* o, float v){ o[0] = v; }

extern "C" void kernel_launch(void* const* d_in, const int* in_sizes, int n_in,
                              void* d_out, int out_size, void* d_ws, size_t ws_size,
                              hipStream_t stream)
{
    const int*   bh   = (const int*)d_in[0];
    const int*   br   = (const int*)d_in[1];
    const int*   bt   = (const int*)d_in[2];
    const float* ent  = (const float*)d_in[3];
    const float* rel  = (const float*)d_in[4];
    const float* ent1 = (const float*)d_in[5];
    const float* rel1 = (const float*)d_in[6];
    const float* Wih_f = (const float*)d_in[7];
    const float* Whh_f = (const float*)d_in[8];
    const float* b_f   = (const float*)d_in[9];
    const float* Wih_b = (const float*)d_in[10];
    const float* Whh_b = (const float*)d_in[11];
    const float* b_b   = (const float*)d_in[12];
    const float* Wih_p = (const float*)d_in[13];
    const float* Whh_p = (const float*)d_in[14];
    const float* b_p   = (const float*)d_in[15];
    const float* W1 = (const float*)d_in[16];
    const float* a1 = (const float*)d_in[17];
    const float* W2 = (const float*)d_in[18];
    const float* a2 = (const float*)d_in[19];

    char* wsb = (char*)d_ws;
    size_t off = 0;
    auto alloc = [&](size_t bytes) -> char* {
        char* p = wsb + off;
        off += (bytes + 255) & ~(size_t)255;
        return p;
    };
    unsigned short* Pfe = (unsigned short*)alloc((size_t)14541*400*2);
    unsigned short* Pbe = (unsigned short*)alloc((size_t)14541*400*2);
    unsigned short* Ppe = (unsigned short*)alloc((size_t)14541*400*2);
    unsigned short* Pfr = (unsigned short*)alloc((size_t)237*400*2);
    unsigned short* Pbr = (unsigned short*)alloc((size_t)237*400*2);
    unsigned short* Ppr = (unsigned short*)alloc((size_t)237*400*2);
    unsigned short* Asw3 = (unsigned short*)alloc((size_t)153600*2);
    unsigned short* Wsw3 = (unsigned short*)alloc((size_t)153600*2);
    float* bI3 = (float*)alloc(1200*4);
    float* w1a = (float*)alloc(600*4);
    float* w1b = (float*)alloc(600*4);
    float* w2a = (float*)alloc(100*4);
    float* w2b = (float*)alloc(100*4);
    float* z   = (float*)alloc((size_t)2048*600*4);
    float* z2  = (float*)alloc((size_t)2048*100*4);

    float* dout  = (float*)d_out;
    float* out0  = dout;              // out2[:,0,:]  1024*600
    float* oatt  = dout + 614400;     // out_att      2048*600
    float* op0   = dout + 1843200;    // op2[:,0,:]   1024*100
    float* oatt2 = dout + 1945600;    // output_att   2048*100

    if (ws_size < off){
        k_sentinel<<<1,1,0,stream>>>(dout, (float)ws_size);
        return;
    }

    k_prep<<<1376, 256, 0, stream>>>(Wih_f, Wih_b, Wih_p, Whh_f, Whh_b, Whh_p,
                                     b_f, b_b, b_p, W1, a1, W2, a2,
                                     Asw3, Wsw3, bI3, w1a, w1b, w2a, w2b);

    k_projm<<<dim3(228,6), 256, 0, stream>>>(ent, rel, ent1, rel1, Wsw3, bI3,
                                             Pfe, Pfr, Pbe, Pbr, Ppe, Ppr);

    k_fused<<<2048, 256, 0, stream>>>(bh, br, bt, Pfe, Pfr, Pbe, Pbr, Ppe, Ppr,
                                      Asw3, w1a, w1b, w2a, w2b, z, z2, out0, op0);

    k_post<<<dim3(128,4), 256, 16*600*4, stream>>>(z, z2, W1, W2, oatt, oatt2);
}